// Round 6
// baseline (56.335 us; speedup 1.0000x reference)
//
#include <hip/hip_runtime.h>
#include <cfloat>

#define NS 7
#define NC 256
#define NH 64
#define NW 64
#define NR 128

// Kernel 1: transpose (C,H,W) -> (H,W,C) into d_ws. Grid = 64 h * 4 c-quarters.
__global__ __launch_bounds__(256) void transpose_chw_hwc(
    const float* __restrict__ f, float* __restrict__ ft)
{
    __shared__ float tile[64][65];   // [w][c], pad 65 -> conflict-free both phases
    const int tid = threadIdx.x;
    const int h   = blockIdx.x >> 2;
    const int c0  = (blockIdx.x & 3) * 64;

    #pragma unroll
    for (int k = 0; k < 16; ++k) {
        int q = tid + k * 256;
        int c = q >> 6;          // 0..63 within quarter
        int w = q & 63;          // lane-consecutive -> coalesced 256B reads
        tile[w][c] = f[(size_t)(c0 + c) * (NH * NW) + h * NW + w];
    }
    __syncthreads();
    #pragma unroll
    for (int k = 0; k < 16; ++k) {
        int q = tid + k * 256;
        int w = q >> 6;
        int c = q & 63;          // lane-consecutive -> coalesced 256B writes
        ft[(size_t)h * (NW * NC) + w * NC + c0 + c] = tile[w][c];
    }
}

// Kernel 2: wave = (roi, bin), lane = channel. Uniform window bounds per wave,
// coalesced 256B channel reads, LDS result staging, contiguous block write.
__global__ __launch_bounds__(512) void roi_pool_hwc(
    const float* __restrict__ ft, const int* __restrict__ rois,
    float* __restrict__ out)
{
    __shared__ float res[64 * NS * NS];   // [c][bin] = 12.25 KB
    const int tid = threadIdx.x;
    const int r   = blockIdx.x >> 2;      // roi
    const int c0  = (blockIdx.x & 3) * 64;

    const int x1 = rois[4 * r + 0];       // H range
    const int y1 = rois[4 * r + 1];       // W range
    const int x2 = rois[4 * r + 2];
    const int y2 = rois[4 * r + 3];
    const int Lh = x2 - x1 + 1;
    const int Lw = y2 - y1 + 1;

    // 64 ch * 49 bins = 3136 outputs, 512 threads: each wave-iter is ONE bin.
    for (int o = tid; o < 64 * NS * NS; o += 512) {
        int bin = __builtin_amdgcn_readfirstlane(o >> 6);  // wave-uniform
        int c   = o & 63;                                   // = lane
        int i   = bin / NS;
        int j   = bin % NS;

        int h0 = x1 + (i * Lh) / NS;
        int h1 = x1 + ((i + 1) * Lh + NS - 1) / NS;
        int w0 = y1 + (j * Lw) / NS;
        int w1 = y1 + ((j + 1) * Lw + NS - 1) / NS;

        float m = -FLT_MAX;
        for (int h = h0; h < h1; ++h) {
            const float* p = ft + ((size_t)(h * NW + w0)) * NC + c0 + c;
            for (int w = w0; w < w1; ++w) {   // uniform trip count, indep loads
                m = fmaxf(m, *p);
                p += NC;
            }
        }
        res[c * (NS * NS) + bin] = m;   // 49-stride scatter: 2-way alias, free
    }

    __syncthreads();

    // Contiguous 3136-float block for (r, c0..c0+63, all bins): coalesced.
    const size_t base = ((size_t)r * NC + c0) * (NS * NS);
    for (int t = tid; t < 64 * NS * NS; t += 512)
        out[base + t] = res[t];
}

extern "C" void kernel_launch(void* const* d_in, const int* in_sizes, int n_in,
                              void* d_out, int out_size, void* d_ws, size_t ws_size,
                              hipStream_t stream)
{
    const float* feature_map = (const float*)d_in[0];
    const int*   rois        = (const int*)d_in[1];
    float*       out         = (float*)d_out;
    float*       ft          = (float*)d_ws;   // 4 MB HWC scratch

    transpose_chw_hwc<<<NH * 4, 256, 0, stream>>>(feature_map, ft);
    roi_pool_hwc<<<NR * 4, 512, 0, stream>>>(ft, rois, out);
}

// Round 7
// 42.456 us; speedup vs baseline: 1.3269x; 1.3269x over previous
//
#include <hip/hip_runtime.h>
#include <cfloat>

#define NS 7
#define NC 256
#define NH 64
#define NW 64
#define NR 128
#define SW 76   // stripe row stride in floats (even; max read idx 73)

// Wave = one channel, 4 rois sequentially. Block = 4 waves (4 channels).
// Grid = 64 channel-quads * 32 roi-quads = 2048 blocks = 8/CU, 32 waves/CU.
// Phase 1: per h-bin column-max, 2 rows x 32 float2 lanes per coalesced global
// load, 7-bin independent volleys, permlane32_swap row fold (VALU only).
// Phase 2: wave-private LDS stripe, 6 aligned float2 reads per bin, masked.
__global__ __launch_bounds__(256) void roi_pool_kernel(
    const float* __restrict__ f,
    const int* __restrict__ rois,
    float* __restrict__ out)
{
    __shared__ float stripe_all[4][NS][SW];   // 8.5 KB, wave-private slices

    const int tid  = threadIdx.x;
    const int lane = tid & 63;
    const int wid  = tid >> 6;
    float (*stripe)[SW] = stripe_all[wid];

    const int cq = blockIdx.x >> 5;   // 0..63  (consecutive blocks share channels)
    const int g  = blockIdx.x & 31;   // roi-quad 0..31
    const int c  = cq * 4 + wid;

    const float* fc = f + (size_t)c * (NH * NW);
    const int l31  = lane & 63 & 31;
    const int half = lane >> 5;

    // bin decomposition for phase 2 (clamped so inactive lanes stay in-range)
    const int bl = lane < NS * NS ? lane : NS * NS - 1;
    const int bi = bl / NS;
    const int bj = bl - bi * NS;

    for (int rr = 0; rr < 4; ++rr) {
        const int r  = g * 4 + rr;
        const int x1 = rois[4*r+0], y1 = rois[4*r+1];   // x->H, y->W
        const int x2 = rois[4*r+2], y2 = rois[4*r+3];
        const unsigned Lh = (unsigned)(x2 - x1 + 1);
        const unsigned Lw = (unsigned)(y2 - y1 + 1);

        const int d0    = y1 >> 1;                 // first float2 unit
        const int dspan = (y2 >> 1) - d0 + 1;      // <= 32 always
        const bool wact = (l31 < dspan);
        const int  dcl  = d0 + (wact ? l31 : dspan - 1);   // clamped: 2*dcl+1 <= 63

        // h-bin bounds (wave-uniform -> SGPRs, scalar branches)
        int hs[NS], he[NS];
        #pragma unroll
        for (int i = 0; i < NS; ++i) {
            hs[i] = x1 + (int)((unsigned)(i * Lh) / NS);
            he[i] = x1 + (int)(((unsigned)((i + 1) * Lh) + NS - 1) / NS);
        }

        // ---- Phase 1: k=0 volley, 7 independent coalesced loads ----
        float2 acc[NS];
        #pragma unroll
        for (int i = 0; i < NS; ++i) {
            int row  = hs[i] + half;
            bool v   = wact && (row < he[i]);
            int rowc = v ? row : hs[i];
            float2 t = *(const float2*)(fc + rowc * NW + dcl * 2);
            acc[i].x = v ? t.x : -FLT_MAX;
            acc[i].y = v ? t.y : -FLT_MAX;
        }
        // leftover row-pair volleys (uniform trip; avg ~0.6 total extra pairs)
        int mp = (int)(((Lh + NS - 1) / NS + 2) >> 1);   // >= max pairs per bin
        for (int k = 1; k < mp; ++k) {
            #pragma unroll
            for (int i = 0; i < NS; ++i) {
                int row0 = hs[i] + 2 * k;
                if (row0 < he[i]) {               // wave-uniform branch
                    int row  = row0 + half;
                    bool v   = wact && (row < he[i]);
                    int rowc = v ? row : row0;
                    float2 t = *(const float2*)(fc + rowc * NW + dcl * 2);
                    acc[i].x = fmaxf(acc[i].x, v ? t.x : -FLT_MAX);
                    acc[i].y = fmaxf(acc[i].y, v ? t.y : -FLT_MAX);
                }
            }
        }

        // ---- fold lane-halves (rows) with permlane32_swap, write stripe ----
        #pragma unroll
        for (int i = 0; i < NS; ++i) {
            float ax = acc[i].x, bx = acc[i].x;
            float ay = acc[i].y, by = acc[i].y;
            asm("v_permlane32_swap_b32 %0, %1" : "+v"(ax), "+v"(bx));
            asm("v_permlane32_swap_b32 %0, %1" : "+v"(ay), "+v"(by));
            float mx = fmaxf(ax, bx);
            float my = fmaxf(ay, by);
            if (half == 0 && wact) {
                *(float2*)&stripe[i][2 * dcl] = make_float2(mx, my);
            }
        }

        // ---- Phase 2: per-bin max over stripe, 6 aligned float2 reads ----
        {
            int wsj = y1 + (int)((unsigned)(bj * Lw) / NS);
            int wej = y1 + (int)(((unsigned)((bj + 1) * Lw) + NS - 1) / NS);
            int base2 = wsj & ~1;                  // 8B-aligned start
            float m = -FLT_MAX;
            #pragma unroll
            for (int k = 0; k < 6; ++k) {          // covers span <= 11
                float2 v = *(const float2*)&stripe[bi][base2 + 2 * k];
                int w0 = base2 + 2 * k;
                m = fmaxf(m, (w0     >= wsj && w0     < wej) ? v.x : -FLT_MAX);
                m = fmaxf(m, (w0 + 1 < wej)                  ? v.y : -FLT_MAX);
            }
            if (lane < NS * NS)
                out[((size_t)r * NC + c) * (NS * NS) + lane] = m;
        }
    }
}

extern "C" void kernel_launch(void* const* d_in, const int* in_sizes, int n_in,
                              void* d_out, int out_size, void* d_ws, size_t ws_size,
                              hipStream_t stream)
{
    const float* feature_map = (const float*)d_in[0];
    const int*   rois        = (const int*)d_in[1];
    float*       out         = (float*)d_out;

    const int grid  = 64 * 32;   // 2048 blocks
    const int block = 256;

    roi_pool_kernel<<<grid, block, 0, stream>>>(feature_map, rois, out);
}

// Round 8
// 29.282 us; speedup vs baseline: 1.9239x; 1.4499x over previous
//
#include <hip/hip_runtime.h>
#include <cfloat>

#define NS 7
#define NC 256
#define NH 64
#define NW 64
#define NR 128

// Kernel 1: transpose (C,H,W) -> (H,W,C) into d_ws. Grid = 64 h * 4 c-quarters.
__global__ __launch_bounds__(256) void transpose_chw_hwc(
    const float* __restrict__ f, float* __restrict__ ft)
{
    __shared__ float tile[64][65];   // [w][c]
    const int tid = threadIdx.x;
    const int h   = blockIdx.x >> 2;
    const int c0  = (blockIdx.x & 3) * 64;

    #pragma unroll
    for (int k = 0; k < 4; ++k) {
        int q  = tid + k * 256;        // 0..1023
        int c  = q >> 4;               // 0..63
        int w4 = (q & 15) * 4;         // quad along w
        float4 v = *(const float4*)(f + (size_t)(c0 + c) * (NH * NW) + h * NW + w4);
        tile[w4 + 0][c] = v.x;
        tile[w4 + 1][c] = v.y;
        tile[w4 + 2][c] = v.z;
        tile[w4 + 3][c] = v.w;
    }
    __syncthreads();
    #pragma unroll
    for (int k = 0; k < 4; ++k) {
        int q  = tid + k * 256;
        int w  = q >> 4;               // 0..63
        int c4 = (q & 15) * 4;         // quad along c
        float4 v = make_float4(tile[w][c4 + 0], tile[w][c4 + 1],
                               tile[w][c4 + 2], tile[w][c4 + 3]);
        *(float4*)(ft + (size_t)h * (NW * NC) + w * NC + c0 + c4) = v;
    }
}

// Kernel 2: wave = (r, i-bin, j-half, c-group of 64). lane = channel.
// All loop bounds wave-uniform (scalar), loads coalesced 256B, issued in
// 8-wide independent volleys; duplicate in-window reads replace edge masks.
__global__ __launch_bounds__(256) void roi_pool_hwc(
    const float* __restrict__ ft, const int* __restrict__ rois,
    float* __restrict__ out)
{
    const int lane = threadIdx.x & 63;
    const int cg   = threadIdx.x >> 6;
    const int c    = cg * 64 + lane;

    int t = blockIdx.x;               // ((r*7 + i)*2 + jg)
    const int jg = t & 1;  t >>= 1;
    const int i  = t % NS;
    const int r  = t / NS;

    const int4 rb = ((const int4*)rois)[r];   // x1,y1,x2,y2 (x->H, y->W)
    const int x1 = rb.x, y1 = rb.y, x2 = rb.z, y2 = rb.w;
    const unsigned Lh = (unsigned)(x2 - x1 + 1);
    const unsigned Lw = (unsigned)(y2 - y1 + 1);

    const int hs = x1 + (int)(((unsigned)i * Lh) / NS);
    const int he = x1 + (int)(((unsigned)(i + 1) * Lh + NS - 1) / NS);

    const int j0 = jg * 4;
    const int nj = 4 - jg;            // 4 bins (j=0..3) or 3 bins (j=4..6)

    int ws[4], sp[4];
    #pragma unroll
    for (int jj = 0; jj < 4; ++jj) {
        int j = j0 + jj;
        int a = y1 + (int)(((unsigned)j * Lw) / NS);
        int b = y1 + (int)(((unsigned)(j + 1) * Lw + NS - 1) / NS);
        ws[jj] = a;
        sp[jj] = b - a;               // >= 1 always
    }
    if (nj == 3) { ws[3] = ws[2]; sp[3] = sp[2]; }   // duplicate, not stored

    int maxsp = max(max(sp[0], sp[1]), max(sp[2], sp[3]));

    float acc[4];
    #pragma unroll
    for (int jj = 0; jj < 4; ++jj) acc[jj] = -FLT_MAX;

    for (int h = hs; h < he; ++h) {
        const float* row = ft + ((size_t)h * NW) * NC + c;
        const float* pj[4];
        #pragma unroll
        for (int jj = 0; jj < 4; ++jj) pj[jj] = row + ws[jj] * NC;

        int k = 0;
        do {                           // uniform trip: ceil(maxsp/2)
            int e0 = 2 * k, e1 = 2 * k + 1;
            float a[4], b[4];
            #pragma unroll
            for (int jj = 0; jj < 4; ++jj) {   // 8 independent coalesced loads
                int o0 = e0 < sp[jj] - 1 ? e0 : sp[jj] - 1;  // clamp: dup read
                int o1 = e1 < sp[jj] - 1 ? e1 : sp[jj] - 1;  // stays in-window
                a[jj] = pj[jj][(size_t)o0 * NC];
                b[jj] = pj[jj][(size_t)o1 * NC];
            }
            #pragma unroll
            for (int jj = 0; jj < 4; ++jj)
                acc[jj] = fmaxf(acc[jj], fmaxf(a[jj], b[jj]));
            ++k;
        } while (2 * k < maxsp);
    }

    const size_t base = ((size_t)r * NC + c) * (NS * NS) + i * NS + j0;
    #pragma unroll
    for (int jj = 0; jj < 4; ++jj)
        if (jj < nj) out[base + jj] = acc[jj];
}

extern "C" void kernel_launch(void* const* d_in, const int* in_sizes, int n_in,
                              void* d_out, int out_size, void* d_ws, size_t ws_size,
                              hipStream_t stream)
{
    const float* feature_map = (const float*)d_in[0];
    const int*   rois        = (const int*)d_in[1];
    float*       out         = (float*)d_out;
    float*       ft          = (float*)d_ws;   // 4 MB HWC scratch

    transpose_chw_hwc<<<NH * 4, 256, 0, stream>>>(feature_map, ft);
    roi_pool_hwc<<<NR * NS * 2, 256, 0, stream>>>(ft, rois, out);
}